// Round 11
// baseline (307.792 us; speedup 1.0000x reference)
//
#include <hip/hip_runtime.h>
#include <hip/hip_cooperative_groups.h>
#include <cstdint>

namespace cg = cooperative_groups;

typedef __attribute__((ext_vector_type(8))) short short8;
typedef __attribute__((ext_vector_type(4))) float f32x4;
typedef unsigned int u32;
typedef unsigned short u16;

#define NTOK 2304
#define CDIM 384

__device__ __forceinline__ u16 f2bf(float f) {
    u32 u = __builtin_bit_cast(u32, f);
    u32 r = (u + 0x7FFFu + ((u >> 16) & 1u)) >> 16;
    return (u16)r;
}
__device__ __forceinline__ float bf2f(u32 h) {
    u32 u = h << 16;
    return __builtin_bit_cast(float, u);
}

// ---------------------------------------------------------------------------
// Merged transpose/cast (r9 proven, unchanged).
// ---------------------------------------------------------------------------
__global__ __launch_bounds__(256) void transpose_all(
    const float* __restrict__ x, const float* __restrict__ w_qkv,
    const float* __restrict__ w_out,
    u16* __restrict__ xT, u16* __restrict__ xbf,
    u16* __restrict__ wqkvT, u16* __restrict__ wv, u16* __restrict__ woutT)
{
    __shared__ float tile[64][65];
    const int bz = blockIdx.z;
    const float* src; int Csz; char* dT; char* dC = nullptr;
    int dcCol0 = 0; long dcRowB = 0;
    if (bz < 16) {
        src = x + (long)bz * 384 * 2304; Csz = 2304;
        dT = (char*)(xT + (long)bz * 2304 * 384);
        dC = (char*)(xbf + (long)bz * 384 * 2304);
        dcCol0 = 0; dcRowB = 2304 * 2;
    } else if (bz == 16) {
        if (blockIdx.x >= 18) return;
        src = w_qkv; Csz = 1152;
        dT = (char*)wqkvT; dC = (char*)wv; dcCol0 = 768; dcRowB = 768;
    } else {
        if (blockIdx.x >= 6) return;
        src = w_out; Csz = 384;
        dT = (char*)woutT;
    }
    const int c0 = blockIdx.x * 64;
    const int k0 = blockIdx.y * 64;
    const int t = threadIdx.x;
    const int rr = t >> 2, cc4 = (t & 3) * 16;

    const float* srow = src + (long)(k0 + rr) * Csz + c0 + cc4;
#pragma unroll
    for (int i = 0; i < 4; ++i) {
        float4 v = *(const float4*)(srow + i * 4);
        tile[rr][cc4 + i*4 + 0] = v.x;
        tile[rr][cc4 + i*4 + 1] = v.y;
        tile[rr][cc4 + i*4 + 2] = v.z;
        tile[rr][cc4 + i*4 + 3] = v.w;
    }
    __syncthreads();

    {
        char* drow = dT + (long)(c0 + rr) * (CDIM * 2);
        const int sw = (rr & 7) << 4;
#pragma unroll
        for (int half = 0; half < 2; ++half) {
            u32 pk[4];
#pragma unroll
            for (int i = 0; i < 4; ++i) {
                float v0 = tile[cc4 + half*8 + 2*i][rr];
                float v1 = tile[cc4 + half*8 + 2*i + 1][rr];
                pk[i] = (u32)f2bf(v0) | ((u32)f2bf(v1) << 16);
            }
            uint4 q; q.x = pk[0]; q.y = pk[1]; q.z = pk[2]; q.w = pk[3];
            const int inrow = (k0 + cc4 + half*8) * 2;
            *(uint4*)(drow + (inrow ^ sw)) = q;
        }
    }
    if (dC && c0 >= dcCol0) {
        char* drow = dC + (long)(k0 + rr) * dcRowB;
        const int sw = (rr & 7) << 4;
#pragma unroll
        for (int half = 0; half < 2; ++half) {
            u32 pk[4];
#pragma unroll
            for (int i = 0; i < 4; ++i) {
                float v0 = tile[rr][cc4 + half*8 + 2*i];
                float v1 = tile[rr][cc4 + half*8 + 2*i + 1];
                pk[i] = (u32)f2bf(v0) | ((u32)f2bf(v1) << 16);
            }
            uint4 q; q.x = pk[0]; q.y = pk[1]; q.z = pk[2]; q.w = pk[3];
            const int inrow = (c0 - dcCol0 + cc4 + half*8) * 2;
            *(uint4*)(drow + (inrow ^ sw)) = q;
        }
    }
}

// ---------------------------------------------------------------------------
// GEMM tile core (r9-proven body).
// ---------------------------------------------------------------------------
template<int MODE, int KT>
__device__ __forceinline__ void gemm_core(
    const u16* __restrict__ Ab, const u16* __restrict__ Bb,
    char* __restrict__ Obase, int m0, int n0, int ostride,
    const float* __restrict__ bias, u16* As, u16* Bs)
{
    constexpr int KB = KT * 128;
    const int t = threadIdx.x;
    const int w = t >> 6, l = t & 63;
    const int wm = (w >> 1) * 64, wn = (w & 1) * 64;
    const int srow = t >> 3;
    const int scol = (t & 7) * 16;
    f32x4 acc[4][4] = {};

    auto stage = [&](int buf, int kt) {
        const int kbyte = kt * 128;
#pragma unroll
        for (int i = 0; i < 4; ++i) {
            const int row = srow + i * 32;
            const long so = (long)row * KB + kbyte + scol;
            const int d = buf * 16384 + (i * 256 + t) * 16;
            __builtin_amdgcn_global_load_lds(
                (const __attribute__((address_space(1))) u32*)((const char*)Ab + so),
                (__attribute__((address_space(3))) u32*)((char*)As + d), 16, 0, 0);
            __builtin_amdgcn_global_load_lds(
                (const __attribute__((address_space(1))) u32*)((const char*)Bb + so),
                (__attribute__((address_space(3))) u32*)((char*)Bs + d), 16, 0, 0);
        }
    };

    stage(0, 0);
    __syncthreads();
    int cur = 0;
#pragma unroll 1
    for (int kt = 0; kt < KT; ++kt) {
        if (kt < KT - 1) stage(cur ^ 1, kt + 1);
        const char* Ac = (const char*)As + cur * 16384;
        const char* Bc = (const char*)Bs + cur * 16384;
#pragma unroll
        for (int kk = 0; kk < 2; ++kk) {
            short8 af[4], bfr[4];
#pragma unroll
            for (int mi = 0; mi < 4; ++mi) {
                const int m = wm + mi * 16 + (l & 15);
                const int off = m * 128 + ((kk * 64 + (l >> 4) * 16) ^ ((m & 7) << 4));
                af[mi] = *(const short8*)(Ac + off);
            }
#pragma unroll
            for (int ni = 0; ni < 4; ++ni) {
                const int n = wn + ni * 16 + (l & 15);
                const int off = n * 128 + ((kk * 64 + (l >> 4) * 16) ^ ((n & 7) << 4));
                bfr[ni] = *(const short8*)(Bc + off);
            }
#pragma unroll
            for (int mi = 0; mi < 4; ++mi)
#pragma unroll
                for (int ni = 0; ni < 4; ++ni)
                    acc[mi][ni] = __builtin_amdgcn_mfma_f32_16x16x32_bf16(
                        af[mi], bfr[ni], acc[mi][ni], 0, 0, 0);
        }
        __syncthreads();
        cur ^= 1;
    }

    if (MODE == 0) {
        u16* O = (u16*)Obase;
#pragma unroll
        for (int mi = 0; mi < 4; ++mi) {
            const int mb = m0 + wm + mi * 16 + (l >> 4) * 4;
#pragma unroll
            for (int ni = 0; ni < 4; ++ni) {
                const int n = n0 + wn + ni * 16 + (l & 15);
#pragma unroll
                for (int r = 0; r < 4; ++r)
                    O[(long)(mb + r) * ostride + n] = f2bf(acc[mi][ni][r]);
            }
        }
    } else if (MODE == 1) {
        float* O = (float*)Obase;
#pragma unroll
        for (int mi = 0; mi < 4; ++mi) {
            const int mb = m0 + wm + mi * 16 + (l >> 4) * 4;
#pragma unroll
            for (int r = 0; r < 4; ++r) {
                const float bb = bias[mb + r];
#pragma unroll
                for (int ni = 0; ni < 4; ++ni) {
                    const int n = n0 + wn + ni * 16 + (l & 15);
                    O[(long)(mb + r) * ostride + n] = acc[mi][ni][r] + bb;
                }
            }
        }
    } else {
#pragma unroll
        for (int mi = 0; mi < 4; ++mi) {
            const int mb = m0 + wm + mi * 16 + (l >> 4) * 4;
#pragma unroll
            for (int ni = 0; ni < 4; ++ni) {
                const int n = n0 + wn + ni * 16 + (l & 15);
#pragma unroll
                for (int r = 0; r < 4; ++r) {
                    const int m = mb + r;
                    const long byteoff = (long)m * (ostride * 2) +
                        (((long)n * 2) ^ ((m & 7) << 4));
                    *(u16*)(Obase + byteoff) = f2bf(acc[mi][ni][r]);
                }
            }
        }
    }
}

// ---------------------------------------------------------------------------
// sm_fold body (r9-proven). shb layout:
// Sp f32[4*2304] @0 | S f32[48*49] @36864 | invk @46272 | invq @46464 |
// Sbf u16[48*64] @46656   (total 52800)
// ---------------------------------------------------------------------------
__device__ __forceinline__ void sm_fold_core(
    const u16* __restrict__ Tp, const u16* __restrict__ wT,
    const float* __restrict__ temp, const u16* __restrict__ woutT,
    u16* __restrict__ W2T, int h, int b, char* shb)
{
    float* Sp  = (float*)shb;
    float* S   = (float*)(shb + 36864);
    float* invk = (float*)(shb + 46272);
    float* invq = (float*)(shb + 46464);
    u16* Sbf = (u16*)(shb + 46656);

    const int t = threadIdx.x;
    const int w = t >> 6, l = t & 63, lr = l & 15, lk = (l >> 4) * 8;
    const int h48 = h * 48;

    const u16* Tk = Tp + ((long)b * 768 + 384 + h48) * CDIM;
    {
        f32x4 acc[3][3] = {};
#pragma unroll
        for (int ks = 0; ks < 3; ++ks) {
            const int k0 = w * 96 + ks * 32 + lk;
            short8 af[3], bfr[3];
#pragma unroll
            for (int mi = 0; mi < 3; ++mi)
                af[mi] = *(const short8*)(Tk + (long)(mi * 16 + lr) * CDIM + k0);
#pragma unroll
            for (int ni = 0; ni < 3; ++ni) {
                const int row = h48 + ni * 16 + lr;
                const char* base = (const char*)wT + (long)row * 768;
                bfr[ni] = *(const short8*)(base + ((k0 * 2) ^ ((row & 7) << 4)));
            }
#pragma unroll
            for (int mi = 0; mi < 3; ++mi)
#pragma unroll
                for (int ni = 0; ni < 3; ++ni)
                    acc[mi][ni] = __builtin_amdgcn_mfma_f32_16x16x32_bf16(
                        af[mi], bfr[ni], acc[mi][ni], 0, 0, 0);
        }
#pragma unroll
        for (int mi = 0; mi < 3; ++mi)
#pragma unroll
            for (int ni = 0; ni < 3; ++ni)
#pragma unroll
                for (int r = 0; r < 4; ++r)
                    Sp[w * 2304 + (mi * 16 + (l >> 4) * 4 + r) * 48 + ni * 16 + lr]
                        = acc[mi][ni][r];
    }
    if (t < 96) {
        const int ch = (t < 48) ? (h48 + t) : (384 + h48 + (t - 48));
        const u16* trow = Tp + ((long)b * 768 + ch) * CDIM;
        const char* wrow = (const char*)wT + (long)ch * 768;
        const int sw = (ch & 7) << 4;
        float s = 0.f;
#pragma unroll 4
        for (int i = 0; i < 48; ++i) {
            short8 tv = *(const short8*)(trow + i * 8);
            short8 wv = *(const short8*)(wrow + ((i * 16) ^ sw));
#pragma unroll
            for (int e = 0; e < 8; ++e)
                s += bf2f((u16)tv[e]) * bf2f((u16)wv[e]);
        }
        float inv = 1.0f / fmaxf(sqrtf(fmaxf(s, 0.f)), 1e-12f);
        if (t < 48) invq[t] = inv; else invk[t - 48] = inv;
    }
    __syncthreads();
    for (int idx = t; idx < 2304; idx += 256) {
        const int p = idx / 48, q = idx % 48;
        S[p * 49 + q] = Sp[idx] + Sp[2304 + idx] + Sp[4608 + idx] + Sp[6912 + idx];
    }
    __syncthreads();
    if (t < 48) {
        const float sc = temp[h] * invk[t];
        float row[48];
        float mx = -1e30f;
#pragma unroll 8
        for (int q = 0; q < 48; ++q) {
            row[q] = S[t * 49 + q] * sc * invq[q];
            mx = fmaxf(mx, row[q]);
        }
        float ssum = 0.f;
#pragma unroll 8
        for (int q = 0; q < 48; ++q) {
            row[q] = __expf(row[q] - mx);
            ssum += row[q];
        }
        float inv = 1.0f / ssum;
        const int sw = (t & 7) << 4;
#pragma unroll
        for (int g = 0; g < 8; ++g) {
            u32 pk[4];
#pragma unroll
            for (int e = 0; e < 4; ++e) {
                const int q0 = g * 8 + 2 * e;
                float v0 = (q0 < 48) ? row[q0] * inv : 0.f;
                float v1 = (q0 + 1 < 48) ? row[q0 + 1] * inv : 0.f;
                pk[e] = (u32)f2bf(v0) | ((u32)f2bf(v1) << 16);
            }
            uint4 qv; qv.x = pk[0]; qv.y = pk[1]; qv.z = pk[2]; qv.w = pk[3];
            *(uint4*)((char*)Sbf + t * 128 + ((g * 16) ^ sw)) = qv;
        }
    }
    __syncthreads();
    {
        const char* SbfB = (const char*)Sbf;
        const int jw = w * 96;
        f32x4 fac[3][6] = {};
#pragma unroll
        for (int ks = 0; ks < 2; ++ks) {
            const int ka = ks * 64 + (l >> 4) * 16;
            const int kb = h * 96 + ka;
            short8 af[3], bfr[6];
#pragma unroll
            for (int mi = 0; mi < 3; ++mi) {
                const int p = mi * 16 + lr;
                af[mi] = *(const short8*)(SbfB + p * 128 + (ka ^ ((p & 7) << 4)));
            }
#pragma unroll
            for (int ni = 0; ni < 6; ++ni) {
                const int j = jw + ni * 16 + lr;
                bfr[ni] = *(const short8*)((const char*)woutT + (long)j * 768 +
                                           (kb ^ ((j & 7) << 4)));
            }
#pragma unroll
            for (int mi = 0; mi < 3; ++mi)
#pragma unroll
                for (int ni = 0; ni < 6; ++ni)
                    fac[mi][ni] = __builtin_amdgcn_mfma_f32_16x16x32_bf16(
                        af[mi], bfr[ni], fac[mi][ni], 0, 0, 0);
        }
        char* Wb = (char*)W2T + (long)b * 294912;
#pragma unroll
        for (int mi = 0; mi < 3; ++mi)
#pragma unroll
            for (int ni = 0; ni < 6; ++ni)
#pragma unroll
                for (int r = 0; r < 4; ++r) {
                    const int p = mi * 16 + (l >> 4) * 4 + r;
                    const int j = jw + ni * 16 + lr;
                    const long byteoff = (long)j * 768 +
                        (((h48 + p) * 2) ^ ((j & 7) << 4));
                    *(u16*)(Wb + byteoff) = f2bf(fac[mi][ni][r]);
                }
    }
}

// ---------------------------------------------------------------------------
// Cooperative middle (256 blocks, fits even a 1-block/CU validator).
// Phases: G(144) -> Tp(288, looped) -> sm_fold(128) -> W3(144).
// ---------------------------------------------------------------------------
__global__ __launch_bounds__(256, 2) void mid_fused(
    const u16* __restrict__ xbf, const u16* __restrict__ wqkvT,
    const u16* __restrict__ wv, const u16* __restrict__ woutT,
    const float* __restrict__ temp,
    u16* __restrict__ Gs, u16* __restrict__ Tp,
    u16* __restrict__ W2T, u16* __restrict__ W3)
{
    __shared__ __attribute__((aligned(16))) char shb[65536];
    u16* As = (u16*)shb;
    u16* Bs = (u16*)(shb + 32768);
    cg::grid_group grid = cg::this_grid();
    const int bid = blockIdx.x;

    if (bid < 144) {
        const int swzid = (bid & 7) * 18 + (bid >> 3);
        const int b = swzid / 9, rem = swzid % 9;
        const int m0 = (rem % 3) * 128, n0 = (rem / 3) * 128;
        const u16* xb = xbf + (long)b * 384 * NTOK;
        gemm_core<2, 36>(xb + (long)m0 * NTOK, xb + (long)n0 * NTOK,
                         (char*)Gs + (long)b * 294912, m0, n0, 384,
                         nullptr, As, Bs);
    }
    __threadfence();
    grid.sync();

    for (int tile = bid; tile < 288; tile += 256) {
        const int swzid = (tile & 7) * 36 + (tile >> 3);
        const int b = swzid / 18, rem = swzid % 18;
        const int m0 = (rem % 6) * 128, n0 = (rem / 6) * 128;
        gemm_core<0, 6>(wqkvT + (long)m0 * 384,
                        Gs + (long)b * 147456 + (long)n0 * 384,
                        (char*)Tp + (long)b * 589824, m0, n0, 384,
                        nullptr, As, Bs);
    }
    __threadfence();
    grid.sync();

    if (bid < 128) {
        sm_fold_core(Tp, wqkvT, temp, woutT, W2T, bid & 7, bid >> 3, shb);
    }
    __threadfence();
    grid.sync();

    if (bid < 144) {
        const int swzid = (bid & 7) * 18 + (bid >> 3);
        const int b = swzid / 9, rem = swzid % 9;
        const int m0 = (rem % 3) * 128, n0 = (rem / 3) * 128;
        gemm_core<2, 6>(W2T + (long)b * 147456 + (long)m0 * 384,
                        wv + (long)n0 * 384,
                        (char*)W3 + (long)b * 294912, m0, n0, 384,
                        nullptr, As, Bs);
    }
}

// ---------------------------------------------------------------------------
// Standalone kernels (fallback path + final GEMM), r9-proven grids.
// ---------------------------------------------------------------------------
template<int MODE, int KT, int GX, int GY>
__global__ __launch_bounds__(256) void mfma_gemm(
    const u16* __restrict__ A, long aBatch,
    const u16* __restrict__ Bm, long bBatch,
    void* __restrict__ Ovoid, long oBatch, int ostride,
    const float* __restrict__ bias)
{
    constexpr int KE  = KT * 64;
    constexpr int NWG = GX * GY * 16;
    __shared__ __attribute__((aligned(16))) u16 As[2][128 * 64];
    __shared__ __attribute__((aligned(16))) u16 Bs[2][128 * 64];

    const int lid = blockIdx.x + GX * (blockIdx.y + GY * blockIdx.z);
    const int swzid = (lid & 7) * (NWG / 8) + (lid >> 3);
    const int b   = swzid / (GX * GY);
    const int rem = swzid % (GX * GY);
    const int m0 = (rem % GX) * 128, n0 = (rem / GX) * 128;

    char* Obase = (char*)Ovoid + (long)b * oBatch * (MODE == 1 ? 4 : 2);
    gemm_core<MODE, KT>(A + (long)b * aBatch + (long)m0 * KE,
                        Bm + (long)b * bBatch + (long)n0 * KE,
                        Obase, m0, n0, ostride, bias,
                        &As[0][0], &Bs[0][0]);
}

__global__ __launch_bounds__(256) void sm_fold_kernel(
    const u16* __restrict__ Tp, const u16* __restrict__ wT,
    const float* __restrict__ temp, const u16* __restrict__ woutT,
    u16* __restrict__ W2T)
{
    __shared__ __attribute__((aligned(16))) char shb[52800];
    sm_fold_core(Tp, wT, temp, woutT, W2T, blockIdx.x, blockIdx.y, shb);
}

// ---------------------------------------------------------------------------
extern "C" void kernel_launch(void* const* d_in, const int* in_sizes, int n_in,
                              void* d_out, int out_size, void* d_ws, size_t ws_size,
                              hipStream_t stream) {
    const float* x     = (const float*)d_in[0];  // [16][384][2304]
    const float* w_qkv = (const float*)d_in[1];  // [384][1152]
    const float* temp  = (const float*)d_in[2];  // [8]
    const float* w_out = (const float*)d_in[3];  // [384][384]
    const float* b_out = (const float*)d_in[4];  // [384]
    float* out = (float*)d_out;                  // [16][384][2304]

    char* ws = (char*)d_ws;
    const size_t SZ_XBF = 16UL * 384 * 2304 * 2;   // 28.3 MB
    const size_t SZ_XT  = 16UL * 2304 * 384 * 2;   // 28.3 MB
    const size_t SZ_WQT = 1152UL * 384 * 2;        // 0.88 MB
    const size_t SZ_WV  = 384UL * 384 * 2;         // 0.29 MB
    const size_t SZ_WOT = 384UL * 384 * 2 + 256;   // + OOB-read slack
    const size_t SZ_G   = 16UL * 384 * 384 * 2;    // 4.7 MB
    const size_t SZ_TP  = 16UL * 768 * 384 * 2;    // 9.4 MB
    const size_t SZ_W2  = 16UL * 384 * 384 * 2;    // 4.7 MB

    size_t off = 0;
    u16* xbf   = (u16*)(ws + off); off += SZ_XBF;
    u16* xT    = (u16*)(ws + off); off += SZ_XT;
    u16* wqkvT = (u16*)(ws + off); off += SZ_WQT;
    u16* wv    = (u16*)(ws + off); off += SZ_WV;
    u16* woutT = (u16*)(ws + off); off += SZ_WOT;
    u16* Gs    = (u16*)(ws + off); off += SZ_G;
    u16* Tp    = (u16*)(ws + off); off += SZ_TP;
    u16* W2T   = (u16*)(ws + off); off += SZ_W2;
    u16* W3    = (u16*)(ws + off);

    // 1) x -> xT + xbf ; w_qkv -> wqkvT + wv ; w_out -> woutT
    transpose_all<<<dim3(36, 6, 18), 256, 0, stream>>>(
        x, w_qkv, w_out, xT, xbf, wqkvT, wv, woutT);

    // 2) middle: G -> T' -> softmax/fold -> W3
    //    Try cooperative single-kernel; on ANY failure fall back to the
    //    r9-proven 4-launch path (environment-determined, stable per-call).
    {
        void* margs[] = {
            (void*)&xbf, (void*)&wqkvT, (void*)&wv, (void*)&woutT,
            (void*)&temp, (void*)&Gs, (void*)&Tp, (void*)&W2T, (void*)&W3
        };
        hipError_t cerr = hipLaunchCooperativeKernel(
            reinterpret_cast<void*>(mid_fused),
            dim3(256, 1, 1), dim3(256, 1, 1), margs, 0, stream);
        if (cerr != hipSuccess) {
            mfma_gemm<2, 36, 3, 3><<<dim3(3, 3, 16), 256, 0, stream>>>(
                xbf, 384L * 2304, xbf, 384L * 2304, Gs, 384L * 384, 384, nullptr);
            mfma_gemm<0, 6, 6, 3><<<dim3(6, 3, 16), 256, 0, stream>>>(
                wqkvT, 0L, Gs, 384L * 384, Tp, 768L * 384, 384, nullptr);
            sm_fold_kernel<<<dim3(8, 16), 256, 0, stream>>>(
                Tp, wqkvT, temp, woutT, W2T);
            mfma_gemm<2, 6, 3, 3><<<dim3(3, 3, 16), 256, 0, stream>>>(
                W2T, 384L * 384, wv, 0L, W3, 384L * 384, 384, nullptr);
        }
    }

    // 3) out[b] = W3 X + b_out (f32)
    mfma_gemm<1, 6, 3, 18><<<dim3(3, 18, 16), 256, 0, stream>>>(
        W3, 384L * 384, xT, 384L * 2304, out, 384L * 2304, 2304, b_out);
}

// Round 12
// 111.476 us; speedup vs baseline: 2.7611x; 2.7611x over previous
//
#include <hip/hip_runtime.h>
#include <cstdint>

typedef __attribute__((ext_vector_type(8))) short short8;
typedef __attribute__((ext_vector_type(4))) float f32x4;
typedef unsigned int u32;
typedef unsigned short u16;

#define NTOK 2304
#define CDIM 384

__device__ __forceinline__ u16 f2bf(float f) {
    u32 u = __builtin_bit_cast(u32, f);
    u32 r = (u + 0x7FFFu + ((u >> 16) & 1u)) >> 16;
    return (u16)r;
}
__device__ __forceinline__ float bf2f(u32 h) {
    u32 u = h << 16;
    return __builtin_bit_cast(float, u);
}

// ---------------------------------------------------------------------------
// Merged transpose/cast (r9 proven, unchanged).
// bz < 16 : x[bz] [384][2304] -> xT [2304][384] swz AND xbf [384][2304] swz
// bz == 16: w_qkv [384][1152] -> wqkvT [1152][384] swz; cols>=768 -> wv cast
// bz == 17: w_out [384][384]  -> woutT [384 j][384 cc] swz
// ---------------------------------------------------------------------------
__global__ __launch_bounds__(256) void transpose_all(
    const float* __restrict__ x, const float* __restrict__ w_qkv,
    const float* __restrict__ w_out,
    u16* __restrict__ xT, u16* __restrict__ xbf,
    u16* __restrict__ wqkvT, u16* __restrict__ wv, u16* __restrict__ woutT)
{
    __shared__ float tile[64][65];
    const int bz = blockIdx.z;
    const float* src; int Csz; char* dT; char* dC = nullptr;
    int dcCol0 = 0; long dcRowB = 0;
    if (bz < 16) {
        src = x + (long)bz * 384 * 2304; Csz = 2304;
        dT = (char*)(xT + (long)bz * 2304 * 384);
        dC = (char*)(xbf + (long)bz * 384 * 2304);
        dcCol0 = 0; dcRowB = 2304 * 2;
    } else if (bz == 16) {
        if (blockIdx.x >= 18) return;
        src = w_qkv; Csz = 1152;
        dT = (char*)wqkvT; dC = (char*)wv; dcCol0 = 768; dcRowB = 768;
    } else {
        if (blockIdx.x >= 6) return;
        src = w_out; Csz = 384;
        dT = (char*)woutT;
    }
    const int c0 = blockIdx.x * 64;
    const int k0 = blockIdx.y * 64;
    const int t = threadIdx.x;
    const int rr = t >> 2, cc4 = (t & 3) * 16;

    const float* srow = src + (long)(k0 + rr) * Csz + c0 + cc4;
#pragma unroll
    for (int i = 0; i < 4; ++i) {
        float4 v = *(const float4*)(srow + i * 4);
        tile[rr][cc4 + i*4 + 0] = v.x;
        tile[rr][cc4 + i*4 + 1] = v.y;
        tile[rr][cc4 + i*4 + 2] = v.z;
        tile[rr][cc4 + i*4 + 3] = v.w;
    }
    __syncthreads();

    {
        char* drow = dT + (long)(c0 + rr) * (CDIM * 2);
        const int sw = (rr & 7) << 4;
#pragma unroll
        for (int half = 0; half < 2; ++half) {
            u32 pk[4];
#pragma unroll
            for (int i = 0; i < 4; ++i) {
                float v0 = tile[cc4 + half*8 + 2*i][rr];
                float v1 = tile[cc4 + half*8 + 2*i + 1][rr];
                pk[i] = (u32)f2bf(v0) | ((u32)f2bf(v1) << 16);
            }
            uint4 q; q.x = pk[0]; q.y = pk[1]; q.z = pk[2]; q.w = pk[3];
            const int inrow = (k0 + cc4 + half*8) * 2;
            *(uint4*)(drow + (inrow ^ sw)) = q;
        }
    }
    if (dC && c0 >= dcCol0) {
        char* drow = dC + (long)(k0 + rr) * dcRowB;
        const int sw = (rr & 7) << 4;
#pragma unroll
        for (int half = 0; half < 2; ++half) {
            u32 pk[4];
#pragma unroll
            for (int i = 0; i < 4; ++i) {
                float v0 = tile[rr][cc4 + half*8 + 2*i];
                float v1 = tile[rr][cc4 + half*8 + 2*i + 1];
                pk[i] = (u32)f2bf(v0) | ((u32)f2bf(v1) << 16);
            }
            uint4 q; q.x = pk[0]; q.y = pk[1]; q.z = pk[2]; q.w = pk[3];
            const int inrow = (c0 - dcCol0 + cc4 + half*8) * 2;
            *(uint4*)(drow + (inrow ^ sw)) = q;
        }
    }
}

// ---------------------------------------------------------------------------
// GEMM tile core (r9-proven body; KROW = row length in 64-elem units so a
// K-chunk (KT steps) can start inside a longer row).
// MODE 0: bf16 plain; 1: f32+bias; 2: bf16 swz; 3: f32 plain (no bias).
// ---------------------------------------------------------------------------
template<int MODE, int KT, int KROW>
__device__ __forceinline__ void gemm_core(
    const u16* __restrict__ Ab, const u16* __restrict__ Bb,
    char* __restrict__ Obase, int m0, int n0, int ostride,
    const float* __restrict__ bias, u16* As, u16* Bs)
{
    constexpr int KB = KROW * 128;   // row stride in bytes
    const int t = threadIdx.x;
    const int w = t >> 6, l = t & 63;
    const int wm = (w >> 1) * 64, wn = (w & 1) * 64;
    const int srow = t >> 3;
    const int scol = (t & 7) * 16;
    f32x4 acc[4][4] = {};

    auto stage = [&](int buf, int kt) {
        const int kbyte = kt * 128;
#pragma unroll
        for (int i = 0; i < 4; ++i) {
            const int row = srow + i * 32;
            const long so = (long)row * KB + kbyte + scol;
            const int d = buf * 16384 + (i * 256 + t) * 16;
            __builtin_amdgcn_global_load_lds(
                (const __attribute__((address_space(1))) u32*)((const char*)Ab + so),
                (__attribute__((address_space(3))) u32*)((char*)As + d), 16, 0, 0);
            __builtin_amdgcn_global_load_lds(
                (const __attribute__((address_space(1))) u32*)((const char*)Bb + so),
                (__attribute__((address_space(3))) u32*)((char*)Bs + d), 16, 0, 0);
        }
    };

    stage(0, 0);
    __syncthreads();
    int cur = 0;
#pragma unroll 1
    for (int kt = 0; kt < KT; ++kt) {
        if (kt < KT - 1) stage(cur ^ 1, kt + 1);
        const char* Ac = (const char*)As + cur * 16384;
        const char* Bc = (const char*)Bs + cur * 16384;
#pragma unroll
        for (int kk = 0; kk < 2; ++kk) {
            short8 af[4], bfr[4];
#pragma unroll
            for (int mi = 0; mi < 4; ++mi) {
                const int m = wm + mi * 16 + (l & 15);
                const int off = m * 128 + ((kk * 64 + (l >> 4) * 16) ^ ((m & 7) << 4));
                af[mi] = *(const short8*)(Ac + off);
            }
#pragma unroll
            for (int ni = 0; ni < 4; ++ni) {
                const int n = wn + ni * 16 + (l & 15);
                const int off = n * 128 + ((kk * 64 + (l >> 4) * 16) ^ ((n & 7) << 4));
                bfr[ni] = *(const short8*)(Bc + off);
            }
#pragma unroll
            for (int mi = 0; mi < 4; ++mi)
#pragma unroll
                for (int ni = 0; ni < 4; ++ni)
                    acc[mi][ni] = __builtin_amdgcn_mfma_f32_16x16x32_bf16(
                        af[mi], bfr[ni], acc[mi][ni], 0, 0, 0);
        }
        __syncthreads();
        cur ^= 1;
    }

    if (MODE == 0) {
        u16* O = (u16*)Obase;
#pragma unroll
        for (int mi = 0; mi < 4; ++mi) {
            const int mb = m0 + wm + mi * 16 + (l >> 4) * 4;
#pragma unroll
            for (int ni = 0; ni < 4; ++ni) {
                const int n = n0 + wn + ni * 16 + (l & 15);
#pragma unroll
                for (int r = 0; r < 4; ++r)
                    O[(long)(mb + r) * ostride + n] = f2bf(acc[mi][ni][r]);
            }
        }
    } else if (MODE == 1) {
        float* O = (float*)Obase;
#pragma unroll
        for (int mi = 0; mi < 4; ++mi) {
            const int mb = m0 + wm + mi * 16 + (l >> 4) * 4;
#pragma unroll
            for (int r = 0; r < 4; ++r) {
                const float bb = bias[mb + r];
#pragma unroll
                for (int ni = 0; ni < 4; ++ni) {
                    const int n = n0 + wn + ni * 16 + (l & 15);
                    O[(long)(mb + r) * ostride + n] = acc[mi][ni][r] + bb;
                }
            }
        }
    } else if (MODE == 3) {
        float* O = (float*)Obase;
#pragma unroll
        for (int mi = 0; mi < 4; ++mi) {
            const int mb = m0 + wm + mi * 16 + (l >> 4) * 4;
#pragma unroll
            for (int r = 0; r < 4; ++r)
#pragma unroll
                for (int ni = 0; ni < 4; ++ni) {
                    const int n = n0 + wn + ni * 16 + (l & 15);
                    O[(long)(mb + r) * ostride + n] = acc[mi][ni][r];
                }
        }
    } else {
#pragma unroll
        for (int mi = 0; mi < 4; ++mi) {
            const int mb = m0 + wm + mi * 16 + (l >> 4) * 4;
#pragma unroll
            for (int ni = 0; ni < 4; ++ni) {
                const int n = n0 + wn + ni * 16 + (l & 15);
#pragma unroll
                for (int r = 0; r < 4; ++r) {
                    const int m = mb + r;
                    const long byteoff = (long)m * (ostride * 2) +
                        (((long)n * 2) ^ ((m & 7) << 4));
                    *(u16*)(Obase + byteoff) = f2bf(acc[mi][ni][r]);
                }
            }
        }
    }
}

// ---------------------------------------------------------------------------
// G partials: K=2304 split 3x768. 432 blocks; chunk c writes f32 partial
// Gp[c][b][384][384]. All CUs busy (vs 144-block single-shot G).
// ---------------------------------------------------------------------------
__global__ __launch_bounds__(256) void g_partial(
    const u16* __restrict__ xbf, float* __restrict__ Gp)
{
    __shared__ __attribute__((aligned(16))) u16 As[2][128 * 64];
    __shared__ __attribute__((aligned(16))) u16 Bs[2][128 * 64];
    const int lid = blockIdx.x;                  // 0..431
    const int swzid = (lid & 7) * 54 + (lid >> 3);   // bijective (432 = 8*54)
    const int chunk = swzid / 144;
    const int rem2 = swzid % 144;
    const int b = rem2 / 9, rem = rem2 % 9;
    const int m0 = (rem % 3) * 128, n0 = (rem / 3) * 128;
    const u16* xb = xbf + (long)b * 384 * NTOK + chunk * 768;
    gemm_core<3, 12, 36>(xb + (long)m0 * NTOK, xb + (long)n0 * NTOK,
                         (char*)(Gp + ((long)chunk * 16 + b) * 147456),
                         m0, n0, 384, nullptr, &As[0][0], &Bs[0][0]);
}

// ---------------------------------------------------------------------------
// Reduce 3 partials -> bf16 swz G. 8 elems/thread, 1152 blocks.
// ---------------------------------------------------------------------------
__global__ __launch_bounds__(256) void g_reduce(
    const float* __restrict__ Gp, u16* __restrict__ Gs)
{
    const int idx = blockIdx.x * 256 + threadIdx.x;  // 0..294911
    const long e8 = (long)idx * 8;
    const int b = (int)(e8 / 147456);
    const int rmn = (int)(e8 % 147456);
    const int r = rmn / 384, n = rmn % 384;
    const float* p0 = Gp + (long)b * 147456 + rmn;
    const float* p1 = p0 + 16L * 147456;
    const float* p2 = p1 + 16L * 147456;
    float4 a0 = *(const float4*)p0, a1 = *(const float4*)(p0 + 4);
    float4 b0 = *(const float4*)p1, b1 = *(const float4*)(p1 + 4);
    float4 c0 = *(const float4*)p2, c1 = *(const float4*)(p2 + 4);
    float s[8];
    s[0] = a0.x + b0.x + c0.x; s[1] = a0.y + b0.y + c0.y;
    s[2] = a0.z + b0.z + c0.z; s[3] = a0.w + b0.w + c0.w;
    s[4] = a1.x + b1.x + c1.x; s[5] = a1.y + b1.y + c1.y;
    s[6] = a1.z + b1.z + c1.z; s[7] = a1.w + b1.w + c1.w;
    uint4 q;
    q.x = (u32)f2bf(s[0]) | ((u32)f2bf(s[1]) << 16);
    q.y = (u32)f2bf(s[2]) | ((u32)f2bf(s[3]) << 16);
    q.z = (u32)f2bf(s[4]) | ((u32)f2bf(s[5]) << 16);
    q.w = (u32)f2bf(s[6]) | ((u32)f2bf(s[7]) << 16);
    *(uint4*)((char*)Gs + (long)b * 294912 + r * 768 +
              ((n * 2) ^ ((r & 7) << 4))) = q;
}

// ---------------------------------------------------------------------------
// sm_fold (r9-proven). shb: Sp[4*2304]f32 @0 | S[48*49]f32 @36864 |
// invk @46272 | invq @46464 | Sbf u16[48*64] @46656  (total 52800)
// ---------------------------------------------------------------------------
__device__ __forceinline__ void sm_fold_core(
    const u16* __restrict__ Tp, const u16* __restrict__ wT,
    const float* __restrict__ temp, const u16* __restrict__ woutT,
    u16* __restrict__ W2T, int h, int b, char* shb)
{
    float* Sp  = (float*)shb;
    float* S   = (float*)(shb + 36864);
    float* invk = (float*)(shb + 46272);
    float* invq = (float*)(shb + 46464);
    u16* Sbf = (u16*)(shb + 46656);

    const int t = threadIdx.x;
    const int w = t >> 6, l = t & 63, lr = l & 15, lk = (l >> 4) * 8;
    const int h48 = h * 48;

    const u16* Tk = Tp + ((long)b * 768 + 384 + h48) * CDIM;
    {
        f32x4 acc[3][3] = {};
#pragma unroll
        for (int ks = 0; ks < 3; ++ks) {
            const int k0 = w * 96 + ks * 32 + lk;
            short8 af[3], bfr[3];
#pragma unroll
            for (int mi = 0; mi < 3; ++mi)
                af[mi] = *(const short8*)(Tk + (long)(mi * 16 + lr) * CDIM + k0);
#pragma unroll
            for (int ni = 0; ni < 3; ++ni) {
                const int row = h48 + ni * 16 + lr;
                const char* base = (const char*)wT + (long)row * 768;
                bfr[ni] = *(const short8*)(base + ((k0 * 2) ^ ((row & 7) << 4)));
            }
#pragma unroll
            for (int mi = 0; mi < 3; ++mi)
#pragma unroll
                for (int ni = 0; ni < 3; ++ni)
                    acc[mi][ni] = __builtin_amdgcn_mfma_f32_16x16x32_bf16(
                        af[mi], bfr[ni], acc[mi][ni], 0, 0, 0);
        }
#pragma unroll
        for (int mi = 0; mi < 3; ++mi)
#pragma unroll
            for (int ni = 0; ni < 3; ++ni)
#pragma unroll
                for (int r = 0; r < 4; ++r)
                    Sp[w * 2304 + (mi * 16 + (l >> 4) * 4 + r) * 48 + ni * 16 + lr]
                        = acc[mi][ni][r];
    }
    if (t < 96) {
        const int ch = (t < 48) ? (h48 + t) : (384 + h48 + (t - 48));
        const u16* trow = Tp + ((long)b * 768 + ch) * CDIM;
        const char* wrow = (const char*)wT + (long)ch * 768;
        const int sw = (ch & 7) << 4;
        float s = 0.f;
#pragma unroll 4
        for (int i = 0; i < 48; ++i) {
            short8 tv = *(const short8*)(trow + i * 8);
            short8 wv = *(const short8*)(wrow + ((i * 16) ^ sw));
#pragma unroll
            for (int e = 0; e < 8; ++e)
                s += bf2f((u16)tv[e]) * bf2f((u16)wv[e]);
        }
        float inv = 1.0f / fmaxf(sqrtf(fmaxf(s, 0.f)), 1e-12f);
        if (t < 48) invq[t] = inv; else invk[t - 48] = inv;
    }
    __syncthreads();
    for (int idx = t; idx < 2304; idx += 256) {
        const int p = idx / 48, q = idx % 48;
        S[p * 49 + q] = Sp[idx] + Sp[2304 + idx] + Sp[4608 + idx] + Sp[6912 + idx];
    }
    __syncthreads();
    if (t < 48) {
        const float sc = temp[h] * invk[t];
        float row[48];
        float mx = -1e30f;
#pragma unroll 8
        for (int q = 0; q < 48; ++q) {
            row[q] = S[t * 49 + q] * sc * invq[q];
            mx = fmaxf(mx, row[q]);
        }
        float ssum = 0.f;
#pragma unroll 8
        for (int q = 0; q < 48; ++q) {
            row[q] = __expf(row[q] - mx);
            ssum += row[q];
        }
        float inv = 1.0f / ssum;
        const int sw = (t & 7) << 4;
#pragma unroll
        for (int g = 0; g < 8; ++g) {
            u32 pk[4];
#pragma unroll
            for (int e = 0; e < 4; ++e) {
                const int q0 = g * 8 + 2 * e;
                float v0 = (q0 < 48) ? row[q0] * inv : 0.f;
                float v1 = (q0 + 1 < 48) ? row[q0 + 1] * inv : 0.f;
                pk[e] = (u32)f2bf(v0) | ((u32)f2bf(v1) << 16);
            }
            uint4 qv; qv.x = pk[0]; qv.y = pk[1]; qv.z = pk[2]; qv.w = pk[3];
            *(uint4*)((char*)Sbf + t * 128 + ((g * 16) ^ sw)) = qv;
        }
    }
    __syncthreads();
    {
        const char* SbfB = (const char*)Sbf;
        const int jw = w * 96;
        f32x4 fac[3][6] = {};
#pragma unroll
        for (int ks = 0; ks < 2; ++ks) {
            const int ka = ks * 64 + (l >> 4) * 16;
            const int kb = h * 96 + ka;
            short8 af[3], bfr[6];
#pragma unroll
            for (int mi = 0; mi < 3; ++mi) {
                const int p = mi * 16 + lr;
                af[mi] = *(const short8*)(SbfB + p * 128 + (ka ^ ((p & 7) << 4)));
            }
#pragma unroll
            for (int ni = 0; ni < 6; ++ni) {
                const int j = jw + ni * 16 + lr;
                bfr[ni] = *(const short8*)((const char*)woutT + (long)j * 768 +
                                           (kb ^ ((j & 7) << 4)));
            }
#pragma unroll
            for (int mi = 0; mi < 3; ++mi)
#pragma unroll
                for (int ni = 0; ni < 6; ++ni)
                    fac[mi][ni] = __builtin_amdgcn_mfma_f32_16x16x32_bf16(
                        af[mi], bfr[ni], fac[mi][ni], 0, 0, 0);
        }
        char* Wb = (char*)W2T + (long)b * 294912;
#pragma unroll
        for (int mi = 0; mi < 3; ++mi)
#pragma unroll
            for (int ni = 0; ni < 6; ++ni)
#pragma unroll
                for (int r = 0; r < 4; ++r) {
                    const int p = mi * 16 + (l >> 4) * 4 + r;
                    const int j = jw + ni * 16 + lr;
                    const long byteoff = (long)j * 768 +
                        (((h48 + p) * 2) ^ ((j & 7) << 4));
                    *(u16*)(Wb + byteoff) = f2bf(fac[mi][ni][r]);
                }
    }
}

__global__ __launch_bounds__(256) void sm_fold_kernel(
    const u16* __restrict__ Tp, const u16* __restrict__ wT,
    const float* __restrict__ temp, const u16* __restrict__ woutT,
    u16* __restrict__ W2T)
{
    __shared__ __attribute__((aligned(16))) char shb[52800];
    sm_fold_core(Tp, wT, temp, woutT, W2T, blockIdx.x, blockIdx.y, shb);
}

// ---------------------------------------------------------------------------
// Standalone GEMM (r9-proven grids).
// ---------------------------------------------------------------------------
template<int MODE, int KT, int GX, int GY>
__global__ __launch_bounds__(256) void mfma_gemm(
    const u16* __restrict__ A, long aBatch,
    const u16* __restrict__ Bm, long bBatch,
    void* __restrict__ Ovoid, long oBatch, int ostride,
    const float* __restrict__ bias)
{
    constexpr int KE  = KT * 64;
    constexpr int NWG = GX * GY * 16;
    __shared__ __attribute__((aligned(16))) u16 As[2][128 * 64];
    __shared__ __attribute__((aligned(16))) u16 Bs[2][128 * 64];

    const int lid = blockIdx.x + GX * (blockIdx.y + GY * blockIdx.z);
    const int swzid = (lid & 7) * (NWG / 8) + (lid >> 3);
    const int b   = swzid / (GX * GY);
    const int rem = swzid % (GX * GY);
    const int m0 = (rem % GX) * 128, n0 = (rem / GX) * 128;

    char* Obase = (char*)Ovoid + (long)b * oBatch * (MODE == 1 ? 4 : 2);
    gemm_core<MODE, KT, KT>(A + (long)b * aBatch + (long)m0 * KE,
                            Bm + (long)b * bBatch + (long)n0 * KE,
                            Obase, m0, n0, ostride, bias,
                            &As[0][0], &Bs[0][0]);
}

// ---------------------------------------------------------------------------
extern "C" void kernel_launch(void* const* d_in, const int* in_sizes, int n_in,
                              void* d_out, int out_size, void* d_ws, size_t ws_size,
                              hipStream_t stream) {
    const float* x     = (const float*)d_in[0];  // [16][384][2304]
    const float* w_qkv = (const float*)d_in[1];  // [384][1152]
    const float* temp  = (const float*)d_in[2];  // [8]
    const float* w_out = (const float*)d_in[3];  // [384][384]
    const float* b_out = (const float*)d_in[4];  // [384]
    float* out = (float*)d_out;                  // [16][384][2304]

    char* ws = (char*)d_ws;
    const size_t SZ_XBF = 16UL * 384 * 2304 * 2;   // 28.3 MB
    const size_t SZ_XT  = 16UL * 2304 * 384 * 2;   // 28.3 MB
    const size_t SZ_WQT = 1152UL * 384 * 2;        // 0.88 MB
    const size_t SZ_WV  = 384UL * 384 * 2;         // 0.29 MB
    const size_t SZ_WOT = 384UL * 384 * 2 + 256;   // + OOB-read slack
    const size_t SZ_GP  = 3UL * 16 * 384 * 384 * 4; // 28.3 MB (f32 partials)
    const size_t SZ_G   = 16UL * 384 * 384 * 2;    // 4.7 MB
    const size_t SZ_TP  = 16UL * 768 * 384 * 2;    // 9.4 MB
    const size_t SZ_W2  = 16UL * 384 * 384 * 2;    // 4.7 MB

    size_t off = 0;
    u16*   xbf   = (u16*)(ws + off); off += SZ_XBF;
    u16*   xT    = (u16*)(ws + off); off += SZ_XT;
    u16*   wqkvT = (u16*)(ws + off); off += SZ_WQT;
    u16*   wv    = (u16*)(ws + off); off += SZ_WV;
    u16*   woutT = (u16*)(ws + off); off += SZ_WOT;
    float* Gp    = (float*)(ws + off); off += SZ_GP;
    u16*   Gs    = (u16*)(ws + off); off += SZ_G;
    u16*   Tp    = (u16*)(ws + off); off += SZ_TP;
    u16*   W2T   = (u16*)(ws + off); off += SZ_W2;
    u16*   W3    = (u16*)(ws + off);

    // 1) x -> xT + xbf ; w_qkv -> wqkvT + wv ; w_out -> woutT
    transpose_all<<<dim3(36, 6, 18), 256, 0, stream>>>(
        x, w_qkv, w_out, xT, xbf, wqkvT, wv, woutT);
    // 2a) G partials: K-split 3, 432 blocks (all CUs busy)
    g_partial<<<432, 256, 0, stream>>>(xbf, Gp);
    // 2b) reduce partials -> bf16 swz G
    g_reduce<<<1152, 256, 0, stream>>>(Gp, Gs);
    // 3) T'[b] = W_qk^T G (plain bf16 [768][384])
    mfma_gemm<0, 6, 6, 3><<<dim3(6, 3, 16), 256, 0, stream>>>(
        wqkvT, 0L, Gs, 384L * 384, Tp, 768L * 384, 384, nullptr);
    // 4) fused S + softmax + fold -> W2T (bf16 swz)
    sm_fold_kernel<<<dim3(8, 16), 256, 0, stream>>>(
        Tp, wqkvT, temp, woutT, W2T);
    // 5) W3[b] = W2^T Wv (bf16 swz)
    mfma_gemm<2, 6, 3, 3><<<dim3(3, 3, 16), 256, 0, stream>>>(
        W2T, 384L * 384, wv, 0L, W3, 384L * 384, 384, nullptr);
    // 6) out[b] = W3 X + b_out (f32)
    mfma_gemm<1, 6, 3, 18><<<dim3(3, 18, 16), 256, 0, stream>>>(
        W3, 384L * 384, xT, 384L * 2304, out, 384L * 2304, 2304, b_out);
}

// Round 13
// 110.243 us; speedup vs baseline: 2.7919x; 1.0112x over previous
//
#include <hip/hip_runtime.h>
#include <cstdint>

typedef __attribute__((ext_vector_type(8))) short short8;
typedef __attribute__((ext_vector_type(4))) float f32x4;
typedef unsigned int u32;
typedef unsigned short u16;

#define NTOK 2304
#define CDIM 384

__device__ __forceinline__ u16 f2bf(float f) {
    u32 u = __builtin_bit_cast(u32, f);
    u32 r = (u + 0x7FFFu + ((u >> 16) & 1u)) >> 16;
    return (u16)r;
}
__device__ __forceinline__ float bf2f(u32 h) {
    u32 u = h << 16;
    return __builtin_bit_cast(float, u);
}

// ---------------------------------------------------------------------------
// Merged transpose/cast (r9 proven, unchanged).
// ---------------------------------------------------------------------------
__global__ __launch_bounds__(256) void transpose_all(
    const float* __restrict__ x, const float* __restrict__ w_qkv,
    const float* __restrict__ w_out,
    u16* __restrict__ xT, u16* __restrict__ xbf,
    u16* __restrict__ wqkvT, u16* __restrict__ wv, u16* __restrict__ woutT)
{
    __shared__ float tile[64][65];
    const int bz = blockIdx.z;
    const float* src; int Csz; char* dT; char* dC = nullptr;
    int dcCol0 = 0; long dcRowB = 0;
    if (bz < 16) {
        src = x + (long)bz * 384 * 2304; Csz = 2304;
        dT = (char*)(xT + (long)bz * 2304 * 384);
        dC = (char*)(xbf + (long)bz * 384 * 2304);
        dcCol0 = 0; dcRowB = 2304 * 2;
    } else if (bz == 16) {
        if (blockIdx.x >= 18) return;
        src = w_qkv; Csz = 1152;
        dT = (char*)wqkvT; dC = (char*)wv; dcCol0 = 768; dcRowB = 768;
    } else {
        if (blockIdx.x >= 6) return;
        src = w_out; Csz = 384;
        dT = (char*)woutT;
    }
    const int c0 = blockIdx.x * 64;
    const int k0 = blockIdx.y * 64;
    const int t = threadIdx.x;
    const int rr = t >> 2, cc4 = (t & 3) * 16;

    const float* srow = src + (long)(k0 + rr) * Csz + c0 + cc4;
#pragma unroll
    for (int i = 0; i < 4; ++i) {
        float4 v = *(const float4*)(srow + i * 4);
        tile[rr][cc4 + i*4 + 0] = v.x;
        tile[rr][cc4 + i*4 + 1] = v.y;
        tile[rr][cc4 + i*4 + 2] = v.z;
        tile[rr][cc4 + i*4 + 3] = v.w;
    }
    __syncthreads();

    {
        char* drow = dT + (long)(c0 + rr) * (CDIM * 2);
        const int sw = (rr & 7) << 4;
#pragma unroll
        for (int half = 0; half < 2; ++half) {
            u32 pk[4];
#pragma unroll
            for (int i = 0; i < 4; ++i) {
                float v0 = tile[cc4 + half*8 + 2*i][rr];
                float v1 = tile[cc4 + half*8 + 2*i + 1][rr];
                pk[i] = (u32)f2bf(v0) | ((u32)f2bf(v1) << 16);
            }
            uint4 q; q.x = pk[0]; q.y = pk[1]; q.z = pk[2]; q.w = pk[3];
            const int inrow = (k0 + cc4 + half*8) * 2;
            *(uint4*)(drow + (inrow ^ sw)) = q;
        }
    }
    if (dC && c0 >= dcCol0) {
        char* drow = dC + (long)(k0 + rr) * dcRowB;
        const int sw = (rr & 7) << 4;
#pragma unroll
        for (int half = 0; half < 2; ++half) {
            u32 pk[4];
#pragma unroll
            for (int i = 0; i < 4; ++i) {
                float v0 = tile[rr][cc4 + half*8 + 2*i];
                float v1 = tile[rr][cc4 + half*8 + 2*i + 1];
                pk[i] = (u32)f2bf(v0) | ((u32)f2bf(v1) << 16);
            }
            uint4 q; q.x = pk[0]; q.y = pk[1]; q.z = pk[2]; q.w = pk[3];
            const int inrow = (c0 - dcCol0 + cc4 + half*8) * 2;
            *(uint4*)(drow + (inrow ^ sw)) = q;
        }
    }
}

// ---------------------------------------------------------------------------
// GEMM tile core (r9-proven body; KROW = row length in 64-elem units).
// MODE 0: bf16 plain; 1: f32+bias; 2: bf16 swz; 3: f32 plain (no bias).
// ---------------------------------------------------------------------------
template<int MODE, int KT, int KROW>
__device__ __forceinline__ void gemm_core(
    const u16* __restrict__ Ab, const u16* __restrict__ Bb,
    char* __restrict__ Obase, int m0, int n0, int ostride,
    const float* __restrict__ bias, u16* As, u16* Bs)
{
    constexpr int KB = KROW * 128;   // row stride in bytes
    const int t = threadIdx.x;
    const int w = t >> 6, l = t & 63;
    const int wm = (w >> 1) * 64, wn = (w & 1) * 64;
    const int srow = t >> 3;
    const int scol = (t & 7) * 16;
    f32x4 acc[4][4] = {};

    auto stage = [&](int buf, int kt) {
        const int kbyte = kt * 128;
#pragma unroll
        for (int i = 0; i < 4; ++i) {
            const int row = srow + i * 32;
            const long so = (long)row * KB + kbyte + scol;
            const int d = buf * 16384 + (i * 256 + t) * 16;
            __builtin_amdgcn_global_load_lds(
                (const __attribute__((address_space(1))) u32*)((const char*)Ab + so),
                (__attribute__((address_space(3))) u32*)((char*)As + d), 16, 0, 0);
            __builtin_amdgcn_global_load_lds(
                (const __attribute__((address_space(1))) u32*)((const char*)Bb + so),
                (__attribute__((address_space(3))) u32*)((char*)Bs + d), 16, 0, 0);
        }
    };

    stage(0, 0);
    __syncthreads();
    int cur = 0;
#pragma unroll 1
    for (int kt = 0; kt < KT; ++kt) {
        if (kt < KT - 1) stage(cur ^ 1, kt + 1);
        const char* Ac = (const char*)As + cur * 16384;
        const char* Bc = (const char*)Bs + cur * 16384;
#pragma unroll
        for (int kk = 0; kk < 2; ++kk) {
            short8 af[4], bfr[4];
#pragma unroll
            for (int mi = 0; mi < 4; ++mi) {
                const int m = wm + mi * 16 + (l & 15);
                const int off = m * 128 + ((kk * 64 + (l >> 4) * 16) ^ ((m & 7) << 4));
                af[mi] = *(const short8*)(Ac + off);
            }
#pragma unroll
            for (int ni = 0; ni < 4; ++ni) {
                const int n = wn + ni * 16 + (l & 15);
                const int off = n * 128 + ((kk * 64 + (l >> 4) * 16) ^ ((n & 7) << 4));
                bfr[ni] = *(const short8*)(Bc + off);
            }
#pragma unroll
            for (int mi = 0; mi < 4; ++mi)
#pragma unroll
                for (int ni = 0; ni < 4; ++ni)
                    acc[mi][ni] = __builtin_amdgcn_mfma_f32_16x16x32_bf16(
                        af[mi], bfr[ni], acc[mi][ni], 0, 0, 0);
        }
        __syncthreads();
        cur ^= 1;
    }

    if (MODE == 0) {
        u16* O = (u16*)Obase;
#pragma unroll
        for (int mi = 0; mi < 4; ++mi) {
            const int mb = m0 + wm + mi * 16 + (l >> 4) * 4;
#pragma unroll
            for (int ni = 0; ni < 4; ++ni) {
                const int n = n0 + wn + ni * 16 + (l & 15);
#pragma unroll
                for (int r = 0; r < 4; ++r)
                    O[(long)(mb + r) * ostride + n] = f2bf(acc[mi][ni][r]);
            }
        }
    } else if (MODE == 1) {
        float* O = (float*)Obase;
#pragma unroll
        for (int mi = 0; mi < 4; ++mi) {
            const int mb = m0 + wm + mi * 16 + (l >> 4) * 4;
#pragma unroll
            for (int r = 0; r < 4; ++r) {
                const float bb = bias[mb + r];
#pragma unroll
                for (int ni = 0; ni < 4; ++ni) {
                    const int n = n0 + wn + ni * 16 + (l & 15);
                    O[(long)(mb + r) * ostride + n] = acc[mi][ni][r] + bb;
                }
            }
        }
    } else if (MODE == 3) {
        float* O = (float*)Obase;
#pragma unroll
        for (int mi = 0; mi < 4; ++mi) {
            const int mb = m0 + wm + mi * 16 + (l >> 4) * 4;
#pragma unroll
            for (int r = 0; r < 4; ++r)
#pragma unroll
                for (int ni = 0; ni < 4; ++ni) {
                    const int n = n0 + wn + ni * 16 + (l & 15);
                    O[(long)(mb + r) * ostride + n] = acc[mi][ni][r];
                }
        }
    } else {
#pragma unroll
        for (int mi = 0; mi < 4; ++mi) {
            const int mb = m0 + wm + mi * 16 + (l >> 4) * 4;
#pragma unroll
            for (int ni = 0; ni < 4; ++ni) {
                const int n = n0 + wn + ni * 16 + (l & 15);
#pragma unroll
                for (int r = 0; r < 4; ++r) {
                    const int m = mb + r;
                    const long byteoff = (long)m * (ostride * 2) +
                        (((long)n * 2) ^ ((m & 7) << 4));
                    *(u16*)(Obase + byteoff) = f2bf(acc[mi][ni][r]);
                }
            }
        }
    }
}

// ---------------------------------------------------------------------------
// G partials, upper-triangle only: G symmetric -> compute 6 of 9 128-tiles.
// K=2304 split 4x576 (9 K-steps). 4*16*6 = 384 blocks (8*48 swizzle).
// Gp[chunk][b][384][384] f32 (only upper tiles written).
// ---------------------------------------------------------------------------
__global__ __launch_bounds__(256) void g_partial(
    const u16* __restrict__ xbf, float* __restrict__ Gp)
{
    __shared__ __attribute__((aligned(16))) u16 As[2][128 * 64];
    __shared__ __attribute__((aligned(16))) u16 Bs[2][128 * 64];
    const int lid = blockIdx.x;                      // 0..383
    const int swzid = (lid & 7) * 48 + (lid >> 3);   // bijective (384 = 8*48)
    const int chunk = swzid / 96;                    // 0..3
    const int rem2 = swzid % 96;
    const int b = rem2 / 6;
    const int tile = rem2 % 6;                       // -> (ti,tj), ti<=tj
    const int ti = (tile < 3) ? 0 : ((tile < 5) ? 1 : 2);
    const int tj = (tile < 3) ? tile : ((tile < 5) ? tile - 2 : 2);
    const int m0 = ti * 128, n0 = tj * 128;
    const u16* xb = xbf + (long)b * 384 * NTOK + chunk * 576;
    gemm_core<3, 9, 36>(xb + (long)m0 * NTOK, xb + (long)n0 * NTOK,
                        (char*)(Gp + ((long)chunk * 16 + b) * 147456),
                        m0, n0, 384, nullptr, &As[0][0], &Bs[0][0]);
}

// ---------------------------------------------------------------------------
// Reduce 4 partials + mirror: per upper 64x64 tile (i64<=j64), sum the 4
// f32 partials into an LDS tile, then write Gs[r][n] (normal) AND Gs[n][r]
// (transposed) as bf16 swz. Mirror values are bitwise-equal (products
// commute), so diagonal-tile double-writes are benign. Grid (21, 16).
// ---------------------------------------------------------------------------
__global__ __launch_bounds__(256) void g_reduce(
    const float* __restrict__ Gp, u16* __restrict__ Gs)
{
    __shared__ float tile[64][65];
    const int b = blockIdx.y;
    int u = blockIdx.x, i64 = 0;                 // map 0..20 -> (i64<=j64<6)
    while (u >= 6 - i64) { u -= 6 - i64; ++i64; }
    const int j64 = i64 + u;

    const int t = threadIdx.x;
    const int rr = t >> 2, cc4 = (t & 3) * 16;

    const float* base = Gp + (long)b * 147456 +
                        (long)(i64 * 64 + rr) * 384 + j64 * 64 + cc4;
    float acc[16];
#pragma unroll
    for (int i = 0; i < 4; ++i) {
        float4 v = *(const float4*)(base + i * 4);
        acc[i*4+0] = v.x; acc[i*4+1] = v.y; acc[i*4+2] = v.z; acc[i*4+3] = v.w;
    }
#pragma unroll
    for (int c = 1; c < 4; ++c) {
        const float* p = base + (long)c * 16 * 147456;
#pragma unroll
        for (int i = 0; i < 4; ++i) {
            float4 v = *(const float4*)(p + i * 4);
            acc[i*4+0] += v.x; acc[i*4+1] += v.y;
            acc[i*4+2] += v.z; acc[i*4+3] += v.w;
        }
    }
#pragma unroll
    for (int i = 0; i < 16; ++i) tile[rr][cc4 + i] = acc[i];
    __syncthreads();

    char* Gb = (char*)Gs + (long)b * 294912;
    const int sw = (rr & 7) << 4;
    // normal: row i64*64+rr, cols j64*64 + cc4..cc4+15
    {
        char* drow = Gb + (long)(i64 * 64 + rr) * 768;
#pragma unroll
        for (int half = 0; half < 2; ++half) {
            u32 pk[4];
#pragma unroll
            for (int i = 0; i < 4; ++i) {
                float v0 = tile[rr][cc4 + half*8 + 2*i];
                float v1 = tile[rr][cc4 + half*8 + 2*i + 1];
                pk[i] = (u32)f2bf(v0) | ((u32)f2bf(v1) << 16);
            }
            uint4 q; q.x = pk[0]; q.y = pk[1]; q.z = pk[2]; q.w = pk[3];
            const int inrow = (j64 * 64 + cc4 + half*8) * 2;
            *(uint4*)(drow + (inrow ^ sw)) = q;
        }
    }
    // transposed: row j64*64+rr, cols i64*64 + cc4..cc4+15
    {
        char* drow = Gb + (long)(j64 * 64 + rr) * 768;
#pragma unroll
        for (int half = 0; half < 2; ++half) {
            u32 pk[4];
#pragma unroll
            for (int i = 0; i < 4; ++i) {
                float v0 = tile[cc4 + half*8 + 2*i][rr];
                float v1 = tile[cc4 + half*8 + 2*i + 1][rr];
                pk[i] = (u32)f2bf(v0) | ((u32)f2bf(v1) << 16);
            }
            uint4 q; q.x = pk[0]; q.y = pk[1]; q.z = pk[2]; q.w = pk[3];
            const int inrow = (i64 * 64 + cc4 + half*8) * 2;
            *(uint4*)(drow + (inrow ^ sw)) = q;
        }
    }
}

// ---------------------------------------------------------------------------
// sm_fold (r9-proven). shb: Sp[4*2304]f32 @0 | S[48*49]f32 @36864 |
// invk @46272 | invq @46464 | Sbf u16[48*64] @46656  (total 52800)
// ---------------------------------------------------------------------------
__device__ __forceinline__ void sm_fold_core(
    const u16* __restrict__ Tp, const u16* __restrict__ wT,
    const float* __restrict__ temp, const u16* __restrict__ woutT,
    u16* __restrict__ W2T, int h, int b, char* shb)
{
    float* Sp  = (float*)shb;
    float* S   = (float*)(shb + 36864);
    float* invk = (float*)(shb + 46272);
    float* invq = (float*)(shb + 46464);
    u16* Sbf = (u16*)(shb + 46656);

    const int t = threadIdx.x;
    const int w = t >> 6, l = t & 63, lr = l & 15, lk = (l >> 4) * 8;
    const int h48 = h * 48;

    const u16* Tk = Tp + ((long)b * 768 + 384 + h48) * CDIM;
    {
        f32x4 acc[3][3] = {};
#pragma unroll
        for (int ks = 0; ks < 3; ++ks) {
            const int k0 = w * 96 + ks * 32 + lk;
            short8 af[3], bfr[3];
#pragma unroll
            for (int mi = 0; mi < 3; ++mi)
                af[mi] = *(const short8*)(Tk + (long)(mi * 16 + lr) * CDIM + k0);
#pragma unroll
            for (int ni = 0; ni < 3; ++ni) {
                const int row = h48 + ni * 16 + lr;
                const char* base = (const char*)wT + (long)row * 768;
                bfr[ni] = *(const short8*)(base + ((k0 * 2) ^ ((row & 7) << 4)));
            }
#pragma unroll
            for (int mi = 0; mi < 3; ++mi)
#pragma unroll
                for (int ni = 0; ni < 3; ++ni)
                    acc[mi][ni] = __builtin_amdgcn_mfma_f32_16x16x32_bf16(
                        af[mi], bfr[ni], acc[mi][ni], 0, 0, 0);
        }
#pragma unroll
        for (int mi = 0; mi < 3; ++mi)
#pragma unroll
            for (int ni = 0; ni < 3; ++ni)
#pragma unroll
                for (int r = 0; r < 4; ++r)
                    Sp[w * 2304 + (mi * 16 + (l >> 4) * 4 + r) * 48 + ni * 16 + lr]
                        = acc[mi][ni][r];
    }
    if (t < 96) {
        const int ch = (t < 48) ? (h48 + t) : (384 + h48 + (t - 48));
        const u16* trow = Tp + ((long)b * 768 + ch) * CDIM;
        const char* wrow = (const char*)wT + (long)ch * 768;
        const int sw = (ch & 7) << 4;
        float s = 0.f;
#pragma unroll 4
        for (int i = 0; i < 48; ++i) {
            short8 tv = *(const short8*)(trow + i * 8);
            short8 wv = *(const short8*)(wrow + ((i * 16) ^ sw));
#pragma unroll
            for (int e = 0; e < 8; ++e)
                s += bf2f((u16)tv[e]) * bf2f((u16)wv[e]);
        }
        float inv = 1.0f / fmaxf(sqrtf(fmaxf(s, 0.f)), 1e-12f);
        if (t < 48) invq[t] = inv; else invk[t - 48] = inv;
    }
    __syncthreads();
    for (int idx = t; idx < 2304; idx += 256) {
        const int p = idx / 48, q = idx % 48;
        S[p * 49 + q] = Sp[idx] + Sp[2304 + idx] + Sp[4608 + idx] + Sp[6912 + idx];
    }
    __syncthreads();
    if (t < 48) {
        const float sc = temp[h] * invk[t];
        float row[48];
        float mx = -1e30f;
#pragma unroll 8
        for (int q = 0; q < 48; ++q) {
            row[q] = S[t * 49 + q] * sc * invq[q];
            mx = fmaxf(mx, row[q]);
        }
        float ssum = 0.f;
#pragma unroll 8
        for (int q = 0; q < 48; ++q) {
            row[q] = __expf(row[q] - mx);
            ssum += row[q];
        }
        float inv = 1.0f / ssum;
        const int sw = (t & 7) << 4;
#pragma unroll
        for (int g = 0; g < 8; ++g) {
            u32 pk[4];
#pragma unroll
            for (int e = 0; e < 4; ++e) {
                const int q0 = g * 8 + 2 * e;
                float v0 = (q0 < 48) ? row[q0] * inv : 0.f;
                float v1 = (q0 + 1 < 48) ? row[q0 + 1] * inv : 0.f;
                pk[e] = (u32)f2bf(v0) | ((u32)f2bf(v1) << 16);
            }
            uint4 qv; qv.x = pk[0]; qv.y = pk[1]; qv.z = pk[2]; qv.w = pk[3];
            *(uint4*)((char*)Sbf + t * 128 + ((g * 16) ^ sw)) = qv;
        }
    }
    __syncthreads();
    {
        const char* SbfB = (const char*)Sbf;
        const int jw = w * 96;
        f32x4 fac[3][6] = {};
#pragma unroll
        for (int ks = 0; ks < 2; ++ks) {
            const int ka = ks * 64 + (l >> 4) * 16;
            const int kb = h * 96 + ka;
            short8 af[3], bfr[6];
#pragma unroll
            for (int mi = 0; mi < 3; ++mi) {
                const int p = mi * 16 + lr;
                af[mi] = *(const short8*)(SbfB + p * 128 + (ka ^ ((p & 7) << 4)));
            }
#pragma unroll
            for (int ni = 0; ni < 6; ++ni) {
                const int j = jw + ni * 16 + lr;
                bfr[ni] = *(const short8*)((const char*)woutT + (long)j * 768 +
                                           (kb ^ ((j & 7) << 4)));
            }
#pragma unroll
            for (int mi = 0; mi < 3; ++mi)
#pragma unroll
                for (int ni = 0; ni < 6; ++ni)
                    fac[mi][ni] = __builtin_amdgcn_mfma_f32_16x16x32_bf16(
                        af[mi], bfr[ni], fac[mi][ni], 0, 0, 0);
        }
        char* Wb = (char*)W2T + (long)b * 294912;
#pragma unroll
        for (int mi = 0; mi < 3; ++mi)
#pragma unroll
            for (int ni = 0; ni < 6; ++ni)
#pragma unroll
                for (int r = 0; r < 4; ++r) {
                    const int p = mi * 16 + (l >> 4) * 4 + r;
                    const int j = jw + ni * 16 + lr;
                    const long byteoff = (long)j * 768 +
                        (((h48 + p) * 2) ^ ((j & 7) << 4));
                    *(u16*)(Wb + byteoff) = f2bf(fac[mi][ni][r]);
                }
    }
}

__global__ __launch_bounds__(256) void sm_fold_kernel(
    const u16* __restrict__ Tp, const u16* __restrict__ wT,
    const float* __restrict__ temp, const u16* __restrict__ woutT,
    u16* __restrict__ W2T)
{
    __shared__ __attribute__((aligned(16))) char shb[52800];
    sm_fold_core(Tp, wT, temp, woutT, W2T, blockIdx.x, blockIdx.y, shb);
}

// ---------------------------------------------------------------------------
// Standalone GEMM (r9-proven grids).
// ---------------------------------------------------------------------------
template<int MODE, int KT, int GX, int GY>
__global__ __launch_bounds__(256) void mfma_gemm(
    const u16* __restrict__ A, long aBatch,
    const u16* __restrict__ Bm, long bBatch,
    void* __restrict__ Ovoid, long oBatch, int ostride,
    const float* __restrict__ bias)
{
    constexpr int KE  = KT * 64;
    constexpr int NWG = GX * GY * 16;
    __shared__ __attribute__((aligned(16))) u16 As[2][128 * 64];
    __shared__ __attribute__((aligned(16))) u16 Bs[2][128 * 64];

    const int lid = blockIdx.x + GX * (blockIdx.y + GY * blockIdx.z);
    const int swzid = (lid & 7) * (NWG / 8) + (lid >> 3);
    const int b   = swzid / (GX * GY);
    const int rem = swzid % (GX * GY);
    const int m0 = (rem % GX) * 128, n0 = (rem / GX) * 128;

    char* Obase = (char*)Ovoid + (long)b * oBatch * (MODE == 1 ? 4 : 2);
    gemm_core<MODE, KT, KT>(A + (long)b * aBatch + (long)m0 * KE,
                            Bm + (long)b * bBatch + (long)n0 * KE,
                            Obase, m0, n0, ostride, bias,
                            &As[0][0], &Bs[0][0]);
}

// ---------------------------------------------------------------------------
extern "C" void kernel_launch(void* const* d_in, const int* in_sizes, int n_in,
                              void* d_out, int out_size, void* d_ws, size_t ws_size,
                              hipStream_t stream) {
    const float* x     = (const float*)d_in[0];  // [16][384][2304]
    const float* w_qkv = (const float*)d_in[1];  // [384][1152]
    const float* temp  = (const float*)d_in[2];  // [8]
    const float* w_out = (const float*)d_in[3];  // [384][384]
    const float* b_out = (const float*)d_in[4];  // [384]
    float* out = (float*)d_out;                  // [16][384][2304]

    char* ws = (char*)d_ws;
    const size_t SZ_XBF = 16UL * 384 * 2304 * 2;    // 28.3 MB
    const size_t SZ_XT  = 16UL * 2304 * 384 * 2;    // 28.3 MB
    const size_t SZ_WQT = 1152UL * 384 * 2;         // 0.88 MB
    const size_t SZ_WV  = 384UL * 384 * 2;          // 0.29 MB
    const size_t SZ_WOT = 384UL * 384 * 2 + 256;    // + OOB-read slack
    const size_t SZ_GP  = 4UL * 16 * 384 * 384 * 4; // 37.7 MB (f32 partials)
    const size_t SZ_G   = 16UL * 384 * 384 * 2;     // 4.7 MB
    const size_t SZ_TP  = 16UL * 768 * 384 * 2;     // 9.4 MB
    const size_t SZ_W2  = 16UL * 384 * 384 * 2;     // 4.7 MB

    size_t off = 0;
    u16*   xbf   = (u16*)(ws + off); off += SZ_XBF;
    u16*   xT    = (u16*)(ws + off); off += SZ_XT;
    u16*   wqkvT = (u16*)(ws + off); off += SZ_WQT;
    u16*   wv    = (u16*)(ws + off); off += SZ_WV;
    u16*   woutT = (u16*)(ws + off); off += SZ_WOT;
    float* Gp    = (float*)(ws + off); off += SZ_GP;
    u16*   Gs    = (u16*)(ws + off); off += SZ_G;
    u16*   Tp    = (u16*)(ws + off); off += SZ_TP;
    u16*   W2T   = (u16*)(ws + off); off += SZ_W2;
    u16*   W3    = (u16*)(ws + off);

    // 1) x -> xT + xbf ; w_qkv -> wqkvT + wv ; w_out -> woutT
    transpose_all<<<dim3(36, 6, 18), 256, 0, stream>>>(
        x, w_qkv, w_out, xT, xbf, wqkvT, wv, woutT);
    // 2a) G partials: upper-triangle tiles, K-split 4 (384 blocks)
    g_partial<<<384, 256, 0, stream>>>(xbf, Gp);
    // 2b) reduce partials + mirror -> bf16 swz G
    g_reduce<<<dim3(21, 16), 256, 0, stream>>>(Gp, Gs);
    // 3) T'[b] = W_qk^T G (plain bf16 [768][384])
    mfma_gemm<0, 6, 6, 3><<<dim3(6, 3, 16), 256, 0, stream>>>(
        wqkvT, 0L, Gs, 384L * 384, Tp, 768L * 384, 384, nullptr);
    // 4) fused S + softmax + fold -> W2T (bf16 swz)
    sm_fold_kernel<<<dim3(8, 16), 256, 0, stream>>>(
        Tp, wqkvT, temp, woutT, W2T);
    // 5) W3[b] = W2^T Wv (bf16 swz)
    mfma_gemm<2, 6, 3, 3><<<dim3(3, 3, 16), 256, 0, stream>>>(
        W2T, 384L * 384, wv, 0L, W3, 384L * 384, 384, nullptr);
    // 6) out[b] = W3 X + b_out (f32)
    mfma_gemm<1, 6, 3, 18><<<dim3(3, 18, 16), 256, 0, stream>>>(
        W3, 384L * 384, xT, 384L * 2304, out, 384L * 2304, 2304, b_out);
}